// Round 4
// baseline (517.602 us; speedup 1.0000x reference)
//
#include <hip/hip_runtime.h>

// SNN: 3-layer LIF, B=256, T=32, H=1024, IN=2312, OUT=10.
// Round-4: f16 2-plane split with scaled residuals (3 MFMA passes vs bf16's
// 6; all planes f16-normal so no denorm risk), async global_load_lds B/A
// staging with double-buffered LDS and phase-ahead DMA issue, XOR-swizzled
// LDS chunks (2-way conflict = free, DMA-compatible).
//   x = x0 + x1s*2^-12 (f16 planes, x1s normal)
//   W*SC = w0 + w1s*2^-12 (SC=64 for W1, 32 for W2)
//   acc0 += x0*w0          (true * SC)
//   acc1 += x0*w1s + x1s*w0 (true * SC*4096)
//   C = acc0/SC + acc1/(SC*4096) + bias  ; dropped terms ~1e-7 abs.

#define TB 256
#define TT 32
#define TH 1024
#define TIN 2312
#define TOUT 10
#define TM (TT * TB)   // 8192 rows = (t,b)
#define KP1 2368       // TIN padded to multiple of 32

typedef _Float16 f16_t;
typedef f16_t f16x8 __attribute__((ext_vector_type(8)));
typedef f16_t f16x4 __attribute__((ext_vector_type(4)));
typedef float floatx4 __attribute__((ext_vector_type(4)));

__device__ __forceinline__ void dma16(const void* g, void* l) {
  __builtin_amdgcn_global_load_lds(
      (const __attribute__((address_space(1))) unsigned int*)g,
      (__attribute__((address_space(3))) unsigned int*)l, 16, 0, 0);
}

// fragment element offset within a 128x32-f16 plane (row = 64 B), swizzled:
// 16B chunk c of row m stored at slot c ^ ((m>>1)&3)
__device__ __forceinline__ int foff(int m, int q) {
  return m * 32 + ((q ^ ((m >> 1) & 3)) * 8);
}

// W (rows x K) -> 2 scaled f16 planes (rows x Kp), zero-padded K..Kp.
__global__ __launch_bounds__(256) void split_w(const float* __restrict__ W,
                                               f16_t* __restrict__ P,
                                               long plane, int K, int Kp,
                                               float sc) {
  int k4 = (blockIdx.x * 256 + threadIdx.x) * 4;
  if (k4 >= Kp) return;
  long r = blockIdx.y;
  float4 v = (k4 < K) ? *(const float4*)(W + r * (long)K + k4)
                      : float4{0.f, 0.f, 0.f, 0.f};
  float t[4] = {v.x * sc, v.y * sc, v.z * sc, v.w * sc};
  f16x4 a, b;
  #pragma unroll
  for (int e = 0; e < 4; ++e) {
    f16_t h0 = (f16_t)t[e];
    a[e] = h0;
    b[e] = (f16_t)((t[e] - (float)h0) * 4096.f);
  }
  long o = r * (long)Kp + k4;
  *(f16x4*)(P + o) = a;
  *(f16x4*)(P + plane + o) = b;
}

// A row element offset = (r>>8)*sT + (r&255)*sB.
// AF32: A fp32, split in-kernel to 2 planes (As=planes, single-buffered,
//       reg-staged). else: A f16 spikes via DMA (As=double buffer).
// B: always 2 f16 planes via DMA, double-buffered, issued one phase ahead.
template <bool AF32>
__global__ __launch_bounds__(256, 2) void snn_gemm(
    const float* __restrict__ Af, const f16_t* __restrict__ Ab,
    long sT, long sB, const f16_t* __restrict__ Bp, long planeB,
    int Kp, int K, int numT, const float* __restrict__ bias,
    float* __restrict__ C, int N, float s0, float s1) {
  __shared__ f16_t As[2][128 * 32];     // AF32: [plane]; else: [buf]
  __shared__ f16_t Bs[2][2][128 * 32];  // [buf][plane]

  const int tid = threadIdx.x;
  const int wave = tid >> 6, lane = tid & 63;
  const int quad = lane >> 4, l16 = lane & 15;
  const int wm = (wave & 1) * 64, wn = (wave >> 1) * 64;
  const long m0 = (long)blockIdx.x * 128, n0 = (long)blockIdx.y * 128;

  floatx4 acc0[4][4], acc1[4][4];
  #pragma unroll
  for (int i = 0; i < 4; ++i)
    #pragma unroll
    for (int j = 0; j < 4; ++j) {
      acc0[i][j] = (floatx4){0.f, 0.f, 0.f, 0.f};
      acc1[i][j] = (floatx4){0.f, 0.f, 0.f, 0.f};
    }

  // AF32 reg staging: thread covers row m=tid>>1, k-span (tid&1)*16..+15
  const float* arow = nullptr;
  int am = 0, ap = 0, ac0 = 0;
  if constexpr (AF32) {
    const long r = m0 + (tid >> 1);
    arow = Af + (r >> 8) * sT + (r & 255) * sB + (tid & 1) * 16;
    am = tid >> 1;
    ap = (tid >> 2) & 3;
    ac0 = (tid & 1) * 2;
  }
  float4 xr[4];

  auto load_a = [&](int kt) {
    if constexpr (AF32) {
      const int kb = kt * 32;
      const int k0 = kb + (tid & 1) * 16;
      const bool ok0 = (k0 + 8 <= K), ok1 = (k0 + 16 <= K);
      const float4 z = {0.f, 0.f, 0.f, 0.f};
      xr[0] = ok0 ? *(const float4*)(arow + kb) : z;
      xr[1] = ok0 ? *(const float4*)(arow + kb + 4) : z;
      xr[2] = ok1 ? *(const float4*)(arow + kb + 8) : z;
      xr[3] = ok1 ? *(const float4*)(arow + kb + 12) : z;
    }
  };

  auto commit_a = [&]() {
    #pragma unroll
    for (int h = 0; h < 2; ++h) {
      float v[8] = {xr[2 * h].x, xr[2 * h].y, xr[2 * h].z, xr[2 * h].w,
                    xr[2 * h + 1].x, xr[2 * h + 1].y, xr[2 * h + 1].z,
                    xr[2 * h + 1].w};
      f16x8 p0, p1;
      #pragma unroll
      for (int e = 0; e < 8; ++e) {
        f16_t h0 = (f16_t)v[e];
        p0[e] = h0;
        p1[e] = (f16_t)((v[e] - (float)h0) * 4096.f);
      }
      const int off = am * 32 + (((ac0 + h) ^ ap) * 8);
      *(f16x8*)&As[0][off] = p0;
      *(f16x8*)&As[1][off] = p1;
    }
  };

  auto issue_dma = [&](int kt, int buf) {
    const int kb = kt * 32;
    const int ck = (lane & 3) ^ ((lane >> 3) & 3);  // swizzled source chunk
    // B: 2 planes x 8 groups of 16 rows = 16 chunks; wave does 4
    #pragma unroll
    for (int i = 0; i < 4; ++i) {
      const int c = wave * 4 + i;
      const int p = c >> 3, g = c & 7;
      const long n = n0 + g * 16 + (lane >> 2);
      dma16(Bp + p * planeB + n * (long)Kp + kb + ck * 8,
            (void*)&Bs[buf][p][g * 512]);
    }
    if constexpr (!AF32) {
      // A: 8 chunks; wave does 2
      #pragma unroll
      for (int i = 0; i < 2; ++i) {
        const int g = wave * 2 + i;
        const long r = m0 + g * 16 + (lane >> 2);
        dma16(Ab + (r >> 8) * sT + (r & 255) * sB + kb + ck * 8,
              (void*)&As[buf][g * 512]);
      }
    }
  };

  issue_dma(0, 0);
  load_a(0);
  for (int kt = 0; kt < numT; ++kt) {
    const int buf = kt & 1;
    if constexpr (AF32) {
      __syncthreads();  // prev tile's As fragment reads done
      commit_a();
    }
    __syncthreads();  // drains vmcnt -> tile kt DMA data visible; As visible
    if (kt + 1 < numT) {
      load_a(kt + 1);           // global->VGPR, lands during MFMA phase
      issue_dma(kt + 1, buf ^ 1);  // DMA into other buffer, drains next barrier
    }

    // ---- MFMA phase: 48 (AF32) / 32 MFMAs per wave ----
    f16x8 a0[4], b0[4];
    const f16_t* AsA = AF32 ? &As[0][0] : &As[buf][0];
    #pragma unroll
    for (int i = 0; i < 4; ++i)
      a0[i] = *(const f16x8*)&AsA[foff(wm + i * 16 + l16, quad)];
    #pragma unroll
    for (int j = 0; j < 4; ++j)
      b0[j] = *(const f16x8*)&Bs[buf][0][foff(wn + j * 16 + l16, quad)];
    #pragma unroll
    for (int i = 0; i < 4; ++i)
      #pragma unroll
      for (int j = 0; j < 4; ++j)
        acc0[i][j] = __builtin_amdgcn_mfma_f32_16x16x32_f16(a0[i], b0[j],
                                                            acc0[i][j], 0, 0, 0);
    #pragma unroll
    for (int j = 0; j < 4; ++j) {
      f16x8 b1 = *(const f16x8*)&Bs[buf][1][foff(wn + j * 16 + l16, quad)];
      #pragma unroll
      for (int i = 0; i < 4; ++i)
        acc1[i][j] = __builtin_amdgcn_mfma_f32_16x16x32_f16(a0[i], b1,
                                                            acc1[i][j], 0, 0, 0);
    }
    if constexpr (AF32) {
      #pragma unroll
      for (int i = 0; i < 4; ++i) {
        f16x8 a1 = *(const f16x8*)&As[1][foff(wm + i * 16 + l16, quad)];
        #pragma unroll
        for (int j = 0; j < 4; ++j)
          acc1[i][j] = __builtin_amdgcn_mfma_f32_16x16x32_f16(
              a1, b0[j], acc1[i][j], 0, 0, 0);
      }
    }
  }

  // epilogue: C/D layout col=lane&15, row=quad*4+reg
  #pragma unroll
  for (int j = 0; j < 4; ++j) {
    const long col = n0 + wn + j * 16 + l16;
    const float bv = bias[col];
    #pragma unroll
    for (int i = 0; i < 4; ++i) {
      const long row0 = m0 + wm + i * 16 + quad * 4;
      #pragma unroll
      for (int g = 0; g < 4; ++g)
        C[(row0 + g) * (long)N + col] =
            acc0[i][j][g] * s0 + acc1[i][j][g] * s1 + bv;
    }
  }
}

// LIF scan: fp32 currents in, f16 spikes {0,1} out (exact).
__global__ __launch_bounds__(256) void lif_scan_f16(const float* __restrict__ I,
                                                    f16_t* __restrict__ S) {
  int idx = blockIdx.x * 256 + threadIdx.x;
  float v = 0.f, cur = 0.f;
  #pragma unroll
  for (int t = 0; t < TT; ++t) {
    float inp = I[(long)t * (TB * TH) + idx];
    float vd = fmaf(0.05f, cur - v, v);
    float id = cur - 0.2f * cur;
    float s = (vd > 1.0f) ? 1.0f : 0.f;
    v = (1.0f - s) * vd;
    cur = id + inp;
    S[(long)t * (TB * TH) + idx] = (f16_t)s;
  }
}

// GEMM3: one wave per row; I3[r][o] = S2[r][:] . Wout[o][:] + bout[o]
__global__ __launch_bounds__(256) void gemm3_kernel(
    const f16_t* __restrict__ S2, const float* __restrict__ Wout,
    const float* __restrict__ bout, float* __restrict__ I3) {
  int wv = (blockIdx.x * 256 + threadIdx.x) >> 6;
  int lane = threadIdx.x & 63;
  if (wv >= TM) return;
  const f16_t* srow = S2 + (long)wv * TH;
  float acc[TOUT];
  #pragma unroll
  for (int o = 0; o < TOUT; ++o) acc[o] = 0.f;
  const int k0 = lane * 16;  // 64 lanes x 16 = 1024 = TH exactly
  f16x8 sa = *(const f16x8*)(srow + k0);
  f16x8 sb = *(const f16x8*)(srow + k0 + 8);
  #pragma unroll
  for (int e = 0; e < 8; ++e) {
    float u = (float)sa[e], w = (float)sb[e];
    #pragma unroll
    for (int o = 0; o < TOUT; ++o) {
      acc[o] = fmaf(u, Wout[o * TH + k0 + e], acc[o]);
      acc[o] = fmaf(w, Wout[o * TH + k0 + 8 + e], acc[o]);
    }
  }
  #pragma unroll
  for (int off = 32; off > 0; off >>= 1)
    #pragma unroll
    for (int o = 0; o < TOUT; ++o) acc[o] += __shfl_down(acc[o], off, 64);
  if (lane == 0) {
    #pragma unroll
    for (int o = 0; o < TOUT; ++o) I3[(long)wv * TOUT + o] = acc[o] + bout[o];
  }
}

__global__ __launch_bounds__(256) void scan_out(const float* __restrict__ I3,
                                                float* __restrict__ out) {
  int idx = blockIdx.x * blockDim.x + threadIdx.x;
  if (idx >= TB * TOUT) return;
  float v = 0.f, cur = 0.f, cnt = 0.f;
  #pragma unroll
  for (int t = 0; t < TT; ++t) {
    float inp = I3[(long)t * (TB * TOUT) + idx];
    float vd = fmaf(0.05f, cur - v, v);
    float id = cur - 0.2f * cur;
    float s = (vd > 1.0f) ? 1.0f : 0.f;
    v = (1.0f - s) * vd;
    cur = id + inp;
    cnt += s;
  }
  out[idx] = cnt;
}

extern "C" void kernel_launch(void* const* d_in, const int* in_sizes, int n_in,
                              void* d_out, int out_size, void* d_ws,
                              size_t ws_size, hipStream_t stream) {
  const float* x    = (const float*)d_in[0];  // (256,32,2312)
  const float* W1   = (const float*)d_in[1];  // (1024,2312)
  const float* b1   = (const float*)d_in[2];
  const float* W2   = (const float*)d_in[3];  // (1024,1024)
  const float* b2   = (const float*)d_in[4];
  const float* Wout = (const float*)d_in[5];  // (10,1024)
  const float* bout = (const float*)d_in[6];

  // ws: W1p 9.70MB | W2p 4.19MB | bufI 33.55MB | S 16.78MB | buf3 0.33MB
  //   = 64.6 MB. S holds S1, then is overwritten with S2 (S1 dead post-GEMM2).
  f16_t* W1p  = (f16_t*)d_ws;
  f16_t* W2p  = W1p + 2L * TH * KP1;
  float* bufI = (float*)(W2p + 2L * TH * TH);
  f16_t* S    = (f16_t*)(bufI + (long)TM * TH);
  float* buf3 = (float*)(S + (long)TM * TH);

  split_w<<<dim3((KP1 / 4 + 255) / 256, TH), 256, 0, stream>>>(
      W1, W1p, (long)TH * KP1, TIN, KP1, 64.f);
  split_w<<<dim3(1, TH), 256, 0, stream>>>(
      W2, W2p, (long)TH * TH, TH, TH, 32.f);

  // GEMM1: row r=(t,b): x offset = (r&255)*(32*2312) + (r>>8)*2312
  snn_gemm<true><<<dim3(TM / 128, TH / 128), 256, 0, stream>>>(
      x, nullptr, (long)TIN, (long)TT * TIN, W1p, (long)TH * KP1, KP1, TIN,
      KP1 / 32, b1, bufI, TH, 1.f / 64.f, 1.f / 262144.f);

  lif_scan_f16<<<(TB * TH) / 256, 256, 0, stream>>>(bufI, S);

  // GEMM2: S row-major [8192][1024]
  snn_gemm<false><<<dim3(TM / 128, TH / 128), 256, 0, stream>>>(
      nullptr, S, (long)TB * TH, (long)TH, W2p, (long)TH * TH, TH, TH,
      TH / 32, b2, bufI, TH, 1.f / 32.f, 1.f / 131072.f);

  lif_scan_f16<<<(TB * TH) / 256, 256, 0, stream>>>(bufI, S);

  gemm3_kernel<<<(TM * 64) / 256, 256, 0, stream>>>(S, Wout, bout, buf3);

  scan_out<<<(TB * TOUT + 255) / 256, 256, 0, stream>>>(buf3, (float*)d_out);
}